// Round 4
// baseline (1199.368 us; speedup 1.0000x reference)
//
#include <hip/hip_runtime.h>
#include <cstdint>
#include <cstddef>

typedef float  f32x4  __attribute__((ext_vector_type(4)));
typedef __bf16 bf16x8 __attribute__((ext_vector_type(8)));
typedef __bf16 bf16x4 __attribute__((ext_vector_type(4)));

// LDS aperture: low 32 bits of a flat shared pointer are the LDS offset.
#define AS1CV(p) ((const __attribute__((address_space(1))) void*)(uintptr_t)(p))
#define AS3V(p)  ((__attribute__((address_space(3))) void*)(uintptr_t)(p))
// wave-private LDS round-trip ordering (no cross-wave dependency -> no barrier)
#define LGKM0()  asm volatile("s_waitcnt lgkmcnt(0)" ::: "memory")

// ---------------------------------------------------------------------------
// fp32 -> bf16 convert (x).
// ---------------------------------------------------------------------------
__global__ __launch_bounds__(256) void convert_k(
    const float* __restrict__ in, __bf16* __restrict__ out, long n)
{
  const long i = ((long)blockIdx.x * 256 + threadIdx.x) * 4;
  if (i + 3 < n) {
    float4 v = *(const float4*)(in + i);
    __bf16 e[4] = { (__bf16)v.x, (__bf16)v.y, (__bf16)v.z, (__bf16)v.w };
    *(uint2*)(out + i) = *(const uint2*)e;
  }
}

// ---------------------------------------------------------------------------
// Weight transpose + convert: out_bf16[c][r] = (bf16)in_f32[r][c].
// ---------------------------------------------------------------------------
__global__ __launch_bounds__(256) void transpose_f32_bf16_k(
    const float* __restrict__ in, __bf16* __restrict__ out, long inRow, long outRow)
{
  const long tr = (long)blockIdx.y * 64;
  const long tc = (long)blockIdx.x * 64;
  __shared__ float tile[64][65];
  const int tid = threadIdx.x;
  const int rr = tid >> 4, c4 = (tid & 15) * 4;
#pragma unroll
  for (int p = 0; p < 4; p++) {
    const int r = p * 16 + rr;
    float4 v = *(const float4*)(in + (tr + r) * inRow + tc + c4);
    tile[r][c4]     = v.x;
    tile[r][c4 + 1] = v.y;
    tile[r][c4 + 2] = v.z;
    tile[r][c4 + 3] = v.w;
  }
  __syncthreads();
#pragma unroll
  for (int p = 0; p < 2; p++) {
    const int u  = p * 256 + tid;
    const int oc = u >> 3, ch = (u & 7) * 8;
    unsigned short e[8];
#pragma unroll
    for (int j = 0; j < 8; j++) {
      __bf16 b = (__bf16)tile[ch + j][oc];
      e[j] = *(unsigned short*)&b;
    }
    *(uint4*)(out + (tc + oc) * outRow + tr + ch) = *(const uint4*)e;
  }
}

// ---------------------------------------------------------------------------
// bf16 transpose with slices (V relayout): out[c][r] = in[r][c].
// ---------------------------------------------------------------------------
__global__ __launch_bounds__(256) void transpose_bf16_k(
    const __bf16* __restrict__ in, __bf16* __restrict__ out,
    long inRow, long outRow,
    int sliceDiv, long sliceOuter, long sliceInner, long outSlice)
{
  const int s = blockIdx.z;
  const __bf16* ip = in + (long)(s / sliceDiv) * sliceOuter + (long)(s % sliceDiv) * sliceInner;
  __bf16* op = out + (long)s * outSlice;
  const long tr = (long)blockIdx.y * 64;
  const long tc = (long)blockIdx.x * 64;
  __shared__ unsigned short tile[64][66];
  const int tid = threadIdx.x;
  const int rr  = tid >> 3;
  const int c8  = (tid & 7) * 8;
#pragma unroll
  for (int p = 0; p < 2; p++) {
    const int r = p * 32 + rr;
    uint4 v = *(const uint4*)(ip + (tr + r) * inRow + tc + c8);
    const unsigned short* e = (const unsigned short*)&v;
#pragma unroll
    for (int j = 0; j < 8; j++) tile[r][c8 + j] = e[j];
  }
  __syncthreads();
#pragma unroll
  for (int p = 0; p < 2; p++) {
    const int c = p * 32 + rr;
    unsigned short e[8];
#pragma unroll
    for (int j = 0; j < 8; j++) e[j] = tile[c8 + j][c];
    *(uint4*)(op + (tc + c) * outRow + tr + c8) = *(const uint4*)e;
  }
}

// ---------------------------------------------------------------------------
// GEMM: C[M][N] = A[M][K] * BT[N][K]^T, bf16 in, fp32 accum, OutT out.
// 256M x (NR*64)N tile, BK=64, 8 waves (2M x 4N), 512 threads, swizzled LDS.
// 4 phases per K-tile, counted-vmcnt pipeline, setprio around MFMA clusters.
// ---------------------------------------------------------------------------
template <typename OutT, int NR>
__global__ __launch_bounds__(512, 2) void gemm256(
    const __bf16* __restrict__ A, const __bf16* __restrict__ BT,
    OutT* __restrict__ C, int M, int N, int K)
{
  constexpr int BN   = NR * 64;       // block N-tile (192 or 256)
  constexpr int NB   = NR;            // B load-sets per K-tile (64 rows each)
  constexpr int ABUF = 256 * 64;      // elems per A buffer
  constexpr int BBUF = BN * 64;       // elems per B buffer
  const int n0   = blockIdx.x * BN;
  const int m0   = blockIdx.y * 256;
  const int tid  = threadIdx.x;
  const int lane = tid & 63;
  const int wave = tid >> 6;
  const int quad = lane >> 4;
  const int r    = lane & 15;
  const int wm   = wave >> 2;     // 0..1 : 128 M-rows per wave
  const int wn   = wave & 3;      // 0..3 : NR*16 N-cols per wave

  __shared__ __bf16 a_sm[2 * ABUF];   // [buf][row][chunk ^ (row&7)], chunks of 8
  __shared__ __bf16 b_sm[2 * BBUF];

  f32x4 acc[8][NR] = {};

  // staging: set si covers rows si*64 + (tid>>3), chunk tid&7 (swizzled src)
  const int srow = tid >> 3;                       // 0..63
  const int schk = ((tid & 7) ^ (srow & 7)) * 8;   // swizzled source chunk (elems)
  const __bf16* aSrc = A  + (size_t)(m0 + srow) * K + schk;
  const __bf16* bSrc = BT + (size_t)(n0 + srow) * K + schk;
  const size_t rstep = (size_t)64 * K;             // 64 rows of source
  const int wofs = wave * 512;                     // wave-uniform LDS dest base (elems)
  const int NT = K >> 6;

  auto stageA = [&](int si, int ko, int dstbuf) {
    __builtin_amdgcn_global_load_lds(AS1CV(aSrc + si * rstep + ko),
                                     AS3V(a_sm + dstbuf + si * 4096 + wofs), 16, 0, 0);
  };
  auto stageB = [&](int si, int ko, int dstbuf) {
    __builtin_amdgcn_global_load_lds(AS1CV(bSrc + si * rstep + ko),
                                     AS3V(b_sm + dstbuf + si * 4096 + wofs), 16, 0, 0);
  };

  // ---- prologue: stage tile 0 -> buf 0 (same issue order as the loop)
#pragma unroll
  for (int si = 0; si < NB; si++) stageB(si, 0, 0);
  stageA(0, 0, 0); stageA(2, 0, 0); stageA(1, 0, 0); stageA(3, 0, 0);
  asm volatile("s_waitcnt vmcnt(2)" ::: "memory");   // A1,A3 stay in flight
  __builtin_amdgcn_sched_barrier(0);
  __builtin_amdgcn_s_barrier();

#pragma unroll 2
  for (int t = 0; t < NT; ++t) {
    const int abuf = (t & 1) ? ABUF : 0;
    const int bbuf = (t & 1) ? BBUF : 0;
    const int anb  = abuf ^ ABUF;
    const int bnb  = bbuf ^ BBUF;
    const int kn   = ((t + 1 < NT) ? (t + 1) : t) * 64;   // clamped prefetch K offset
    const __bf16* as = a_sm + abuf + (wm * 128 + r) * 64;
    const __bf16* bs = b_sm + bbuf + (wn * (NR * 16) + r) * 64;
    bf16x8 bfr[NR][2];

#pragma unroll
    for (int p = 0; p < 4; p++) {
      // ---- LDS reads for this phase (latency overlaps the barrier below)
      if (p == 0) {
#pragma unroll
        for (int ni = 0; ni < NR; ni++)
#pragma unroll
          for (int kk = 0; kk < 2; kk++)
            bfr[ni][kk] = *(const bf16x8*)(bs + ni * 1024 + (((kk * 4 + quad) ^ (r & 7)) * 8));
      }
      bf16x8 af[2][2];
#pragma unroll
      for (int u = 0; u < 2; u++)
#pragma unroll
        for (int kk = 0; kk < 2; kk++)
          af[u][kk] = *(const bf16x8*)(as + (p * 2 + u) * 1024 + (((kk * 4 + quad) ^ (r & 7)) * 8));

      // ---- prefetch issues for tile t+1 (other buffer; no intra-tile hazard)
      if (p == 0) { stageB(0, kn, bnb); stageB(1, kn, bnb); }
      if (p == 1) {
        if constexpr (NR == 3) { stageB(2, kn, bnb); stageA(0, kn, anb); }
        else                   { stageB(2, kn, bnb); stageB(3, kn, bnb); }
      }
      if (p == 2) {
        if constexpr (NR == 3) { stageA(2, kn, anb); stageA(1, kn, anb); }
        else                   { stageA(0, kn, anb); stageA(2, kn, anb); }
      }
      if (p == 3) {
        if constexpr (NR == 3) { stageA(3, kn, anb); }
        else                   { stageA(1, kn, anb); stageA(3, kn, anb); }
      }

      __builtin_amdgcn_s_barrier();
      __builtin_amdgcn_s_setprio(1);
#pragma unroll
      for (int u = 0; u < 2; u++)
#pragma unroll
        for (int ni = 0; ni < NR; ni++)
#pragma unroll
          for (int kk = 0; kk < 2; kk++)
            acc[p * 2 + u][ni] = __builtin_amdgcn_mfma_f32_16x16x32_bf16(af[u][kk], bfr[ni][kk], acc[p * 2 + u][ni], 0, 0, 0);
      __builtin_amdgcn_s_setprio(0);
      if (p == 1) { asm volatile("s_waitcnt vmcnt(4)" ::: "memory"); __builtin_amdgcn_sched_barrier(0); }
      if (p == 3) { asm volatile("s_waitcnt vmcnt(2)" ::: "memory"); __builtin_amdgcn_sched_barrier(0); }
      __builtin_amdgcn_s_barrier();
    }
  }
  asm volatile("s_waitcnt vmcnt(0)" ::: "memory");     // drain tail loads before LDS dealloc

  // C/D layout: col = lane&15, row = quad*4 + reg
#pragma unroll
  for (int mi = 0; mi < 8; mi++)
#pragma unroll
    for (int ni = 0; ni < NR; ni++) {
      const int col = n0 + wn * (NR * 16) + ni * 16 + r;
#pragma unroll
      for (int g = 0; g < 4; g++) {
        const int row = m0 + wm * 128 + mi * 16 + quad * 4 + g;
        C[(size_t)row * N + col] = (OutT)acc[mi][ni][g];
      }
    }
}

// ---------------------------------------------------------------------------
// RoPE + relayout: qkv[B*T][6144](bf16) -> qr[B][H][T][D], kr[B][KV][T][D]
// ---------------------------------------------------------------------------
__global__ __launch_bounds__(256) void rope_k(
    const __bf16* __restrict__ qkv, __bf16* __restrict__ qr, __bf16* __restrict__ kr)
{
  const int m = blockIdx.x;
  const int b = m >> 11;
  const int t = m & 2047;
  const __bf16* rowp = qkv + (size_t)m * 6144;
  for (int n = threadIdx.x; n < 5120; n += 256) {
    const bool isq  = n < 4096;
    const int local = isq ? n : (n - 4096);
    const int head  = local >> 7;
    const int d     = local & 127;
    const int j     = d & 63;
    const float ex   = (float)(2 * j) / 128.0f;
    const float invf = 1.0f / powf(10000.0f, ex);
    const float ang  = ((float)t * invf) * 2.0f;   // * B=2 per reference quirk
    const float c = cosf(ang), s = sinf(ang);
    const float v0 = (float)rowp[n];
    const float v1 = (float)rowp[n + ((d < 64) ? 64 : -64)];
    const float o  = (d < 64) ? (v0 * c - v1 * s) : (v0 * c + v1 * s);
    if (isq) qr[((size_t)(b * 32 + head) * 2048 + t) * 128 + d] = (__bf16)o;
    else     kr[((size_t)(b * 8  + head) * 2048 + t) * 128 + d] = (__bf16)o;
  }
}

// ---------------------------------------------------------------------------
// Flash attention v2: S^T orientation, Q in registers, XOR-swizzled LDS,
// single-buffer K/V with T14 async-STAGE split: global->reg loads for tile
// jt+1 issued at the TOP of iter jt (latency hides under compute), ds_write
// after the end-of-read barrier. alpha/l broadcast via __shfl (no LDS)
// -> LDS = 40960 B exactly -> up to 4 blocks/CU.
// qr[B][H][T][D], kr[B][KV][T][D], vT[B][KV][D][T] -> y[B][T][H*D] (bf16)
// grid = (T/64, B*H); wave w owns q-rows [16w,16w+16).
// ---------------------------------------------------------------------------
__global__ __launch_bounds__(256, 3) void flash_k(
    const __bf16* __restrict__ qr, const __bf16* __restrict__ kr,
    const __bf16* __restrict__ vT, __bf16* __restrict__ y)
{
  const int qt  = (int)gridDim.x - 1 - (int)blockIdx.x;  // longest blocks first
  const int bh  = blockIdx.y;
  const int b   = bh >> 5;
  const int h   = bh & 31;
  const int kvh = h >> 2;
  const int tq0 = qt * 64;
  const int tid  = threadIdx.x;
  const int lane = tid & 63;
  const int wave = tid >> 6;
  const int quad = lane >> 4;
  const int r    = lane & 15;

  __shared__ __bf16 k_sm[64 * 128];     // [kv][d], chunk^=(row&15)   16 KiB
  __shared__ __bf16 v_sm[128 * 64];     // [d][t],  chunk^=(row&7)    16 KiB
  __shared__ __bf16 p_sm[4][16 * 64];   // per-wave [q][kv], chunk^=(q&7) 8 KiB

  const __bf16* kbase = kr + ((size_t)(b * 8 + kvh) * 2048) * 128;
  const __bf16* vbase = vT + ((size_t)(b * 8 + kvh) * 128) * 2048;

  // Q fragments in registers (B-operand layout): Q[q=wave*16+r][kk*32+quad*8+j]
  bf16x8 qf[4];
  {
    const __bf16* qrow = qr + ((size_t)(b * 32 + h) * 2048 + tq0 + wave * 16 + r) * 128;
#pragma unroll
    for (int kk = 0; kk < 4; kk++)
      qf[kk] = *(const bf16x8*)(qrow + kk * 32 + quad * 8);
  }

  f32x4 Oacc[8] = {};
  float mstate = -1e30f, lstate = 0.0f;
  const float scale = 0.08838834764831845f;   // 1/sqrt(128)

  const int rowK = lane >> 4, cK = lane & 15;   // K staging: 4 rows x 16 chunks
  const int rowV = lane >> 3, cV = lane & 7;    // V staging: 8 rows x 8 chunks

  // T14 reg staging: same global addrs + LDS dests as the verified
  // global_load_lds mapping (dest elem = li*512 + lane*8).
  uint4 kreg[4], vreg[4];
  auto loadKV = [&](int jt) {
#pragma unroll
    for (int i = 0; i < 4; i++) {
      const int li = wave * 4 + i;
      const int rk = li * 4 + rowK;
      kreg[i] = *(const uint4*)(kbase + (size_t)(jt * 64 + rk) * 128 + ((cK ^ (rk & 15)) * 8));
      const int rv = li * 8 + rowV;
      vreg[i] = *(const uint4*)(vbase + (size_t)rv * 2048 + jt * 64 + ((cV ^ (rv & 7)) * 8));
    }
  };
  auto writeKV = [&]() {
#pragma unroll
    for (int i = 0; i < 4; i++) {
      const int li = wave * 4 + i;
      *(uint4*)(k_sm + li * 512 + lane * 8) = kreg[i];   // dep on kreg -> auto vmcnt
      *(uint4*)(v_sm + li * 512 + lane * 8) = vreg[i];
    }
  };

  // prologue: stage tile 0
  loadKV(0);
  writeKV();
  __syncthreads();

  for (int jt = 0; jt <= qt; jt++) {
    const bool pf = (jt < qt);
    // issue next tile's loads NOW; values consumed only after the read-barrier
    if (pf) loadKV(jt + 1);
    __builtin_amdgcn_sched_barrier(0);   // pin load issue above the compute

    // S^T = K·Q^T : lane holds S[kv=mi*16+quad*4+g][q=wave*16+r]
    f32x4 St[4] = {};
    __builtin_amdgcn_s_setprio(1);
#pragma unroll
    for (int kk = 0; kk < 4; kk++)
#pragma unroll
      for (int mi = 0; mi < 4; mi++) {
        bf16x8 kf = *(const bf16x8*)(k_sm + (mi * 16 + r) * 128 + (((kk * 4 + quad) ^ r) * 8));
        St[mi] = __builtin_amdgcn_mfma_f32_16x16x32_bf16(kf, qf[kk], St[mi], 0, 0, 0);
      }
    __builtin_amdgcn_s_setprio(0);

    // online softmax: full row (64 kv) = 16 in-lane values + 4 quads
    const bool diag = (jt == qt);
    const int qabs  = tq0 + wave * 16 + r;
    float p[16];
#pragma unroll
    for (int mi = 0; mi < 4; mi++)
#pragma unroll
      for (int g = 0; g < 4; g++) {
        float v = St[mi][g] * scale;
        if (diag && (jt * 64 + mi * 16 + quad * 4 + g) > qabs) v = -3.0e38f;
        p[mi * 4 + g] = v;
      }
    float mx = p[0];
#pragma unroll
    for (int i = 1; i < 16; i++) mx = fmaxf(mx, p[i]);
    mx = fmaxf(mx, __shfl_xor(mx, 16));
    mx = fmaxf(mx, __shfl_xor(mx, 32));
    const float mnew  = fmaxf(mstate, mx);
    const float alpha = __expf(mstate - mnew);
    mstate = mnew;
    float rs = 0.0f;
#pragma unroll
    for (int i = 0; i < 16; i++) { p[i] = __expf(p[i] - mnew); rs += p[i]; }
    rs += __shfl_xor(rs, 16);
    rs += __shfl_xor(rs, 32);
    lstate = lstate * alpha + rs;

    // P -> p_sm (swizzled [q][kv]): kv = mi*16+quad*4+g, chunk cw = mi*2+(quad>>1)
#pragma unroll
    for (int mi = 0; mi < 4; mi++) {
      bf16x4 pk = { (__bf16)p[mi*4+0], (__bf16)p[mi*4+1], (__bf16)p[mi*4+2], (__bf16)p[mi*4+3] };
      const int cw = mi * 2 + (quad >> 1);
      *(bf16x4*)(&p_sm[wave][r * 64 + ((cw ^ (r & 7)) * 8) + (quad & 1) * 4]) = pk;
    }
    LGKM0();   // wave-private LDS ordering (write -> read below)

    // O rescale: alpha is quad-replicated per q-row -> fetch rows quad*4+g via shfl
    {
      const float a0 = __shfl(alpha, quad * 4 + 0);
      const float a1 = __shfl(alpha, quad * 4 + 1);
      const float a2 = __shfl(alpha, quad * 4 + 2);
      const float a3 = __shfl(alpha, quad * 4 + 3);
#pragma unroll
      for (int dt = 0; dt < 8; dt++) {
        Oacc[dt][0] *= a0; Oacc[dt][1] *= a1; Oacc[dt][2] *= a2; Oacc[dt][3] *= a3;
      }
    }

    // O += P·V  (A = P[q][kv] from p_sm, B = V^T[d][kv] from v_sm)
    __builtin_amdgcn_s_setprio(1);
#pragma unroll
    for (int kk = 0; kk < 2; kk++) {
      bf16x8 pf_ = *(const bf16x8*)(&p_sm[wave][r * 64 + (((kk * 4 + quad) ^ (r & 7)) * 8)]);
#pragma unroll
      for (int dt = 0; dt < 8; dt++) {
        bf16x8 vf = *(const bf16x8*)(v_sm + (dt * 16 + r) * 64 + (((kk * 4 + quad) ^ (r & 7)) * 8));
        Oacc[dt] = __builtin_amdgcn_mfma_f32_16x16x32_bf16(pf_, vf, Oacc[dt], 0, 0, 0);
      }
    }
    __builtin_amdgcn_s_setprio(0);

    __syncthreads();          // all waves done READING tile jt
    if (pf) writeKV();        // stores depend on kreg/vreg -> auto vmcnt wait
    __syncthreads();          // writes visible (compiler adds lgkmcnt before barrier)
  }

  // epilogue: l broadcast via shfl (lstate quad-replicated per q-row)
  const float il0 = 1.0f / __shfl(lstate, quad * 4 + 0);
  const float il1 = 1.0f / __shfl(lstate, quad * 4 + 1);
  const float il2 = 1.0f / __shfl(lstate, quad * 4 + 2);
  const float il3 = 1.0f / __shfl(lstate, quad * 4 + 3);
#pragma unroll
  for (int dt = 0; dt < 8; dt++) {
    const int col = h * 128 + dt * 16 + r;
    const int row = tq0 + wave * 16 + quad * 4;
    y[((size_t)(b * 2048 + row + 0)) * 4096 + col] = (__bf16)(Oacc[dt][0] * il0);
    y[((size_t)(b * 2048 + row + 1)) * 4096 + col] = (__bf16)(Oacc[dt][1] * il1);
    y[((size_t)(b * 2048 + row + 2)) * 4096 + col] = (__bf16)(Oacc[dt][2] * il2);
    y[((size_t)(b * 2048 + row + 3)) * 4096 + col] = (__bf16)(Oacc[dt][3] * il3);
  }
}

// ---------------------------------------------------------------------------
extern "C" void kernel_launch(void* const* d_in, const int* in_sizes, int n_in,
                              void* d_out, int out_size, void* d_ws, size_t ws_size,
                              hipStream_t stream)
{
  const float* x  = (const float*)d_in[0];
  // d_in[1] = mask (pure causal triu -> analytic)
  const float* wq = (const float*)d_in[2];
  const float* wk = (const float*)d_in[3];
  const float* wv = (const float*)d_in[4];
  const float* wo = (const float*)d_in[5];
  float* out = (float*)d_out;

  __bf16* ws  = (__bf16*)d_ws;
  __bf16* xb  = ws;                         // [4096][4096]
  __bf16* wT  = xb  + (size_t)16777216;     // [6144][4096]
  __bf16* qkv = wT  + (size_t)25165824;     // [4096][6144]
  __bf16* qr  = qkv + (size_t)25165824;     // [2][32][2048][128]
  __bf16* kr  = qr  + (size_t)16777216;     // [2][8][2048][128]
  __bf16* vT  = kr  + (size_t)4194304;      // [2][8][128][2048]
  __bf16* y   = xb;                         // alias: xb dead after gemm1
  __bf16* woT = wT;                         // alias: wT dead after gemm1

  dim3 blk(256);
  convert_k<<<dim3(16384), blk, 0, stream>>>(x, xb, 16777216L);
  transpose_f32_bf16_k<<<dim3(64, 64), blk, 0, stream>>>(wq, wT,                     4096L, 4096L);
  transpose_f32_bf16_k<<<dim3(16, 64), blk, 0, stream>>>(wk, wT + (size_t)4096*4096, 1024L, 4096L);
  transpose_f32_bf16_k<<<dim3(16, 64), blk, 0, stream>>>(wv, wT + (size_t)5120*4096, 1024L, 4096L);
  gemm256<__bf16, 3><<<dim3(32, 16), dim3(512), 0, stream>>>(xb, wT, qkv, 4096, 6144, 4096);
  transpose_f32_bf16_k<<<dim3(64, 64), blk, 0, stream>>>(wo, woT, 4096L, 4096L);
  rope_k<<<dim3(4096), blk, 0, stream>>>(qkv, qr, kr);
  transpose_bf16_k<<<dim3(2, 32, 16), blk, 0, stream>>>(qkv + 5120, vT, 6144L, 2048L,
                                                        8, (long)2048 * 6144, 128L, (long)128 * 2048);
  flash_k<<<dim3(32, 64), blk, 0, stream>>>(qr, kr, vT, y);
  gemm256<float, 4><<<dim3(16, 16), dim3(512), 0, stream>>>(y, woT, out, 4096, 4096, 4096);
}

// Round 5
// 829.008 us; speedup vs baseline: 1.4467x; 1.4467x over previous
//
#include <hip/hip_runtime.h>
#include <cstdint>
#include <cstddef>

typedef float  f32x4  __attribute__((ext_vector_type(4)));
typedef __bf16 bf16x8 __attribute__((ext_vector_type(8)));
typedef __bf16 bf16x4 __attribute__((ext_vector_type(4)));

// LDS aperture: low 32 bits of a flat shared pointer are the LDS offset.
#define AS1CV(p) ((const __attribute__((address_space(1))) void*)(uintptr_t)(p))
#define AS3V(p)  ((__attribute__((address_space(3))) void*)(uintptr_t)(p))
// wave-private LDS round-trip ordering (no cross-wave dependency -> no barrier)
#define LGKM0()  asm volatile("s_waitcnt lgkmcnt(0)" ::: "memory")

// ---------------------------------------------------------------------------
// fp32 -> bf16 convert (x).
// ---------------------------------------------------------------------------
__global__ __launch_bounds__(256) void convert_k(
    const float* __restrict__ in, __bf16* __restrict__ out, long n)
{
  const long i = ((long)blockIdx.x * 256 + threadIdx.x) * 4;
  if (i + 3 < n) {
    float4 v = *(const float4*)(in + i);
    __bf16 e[4] = { (__bf16)v.x, (__bf16)v.y, (__bf16)v.z, (__bf16)v.w };
    *(uint2*)(out + i) = *(const uint2*)e;
  }
}

// ---------------------------------------------------------------------------
// Weight transpose + convert: out_bf16[c][r] = (bf16)in_f32[r][c].
// ---------------------------------------------------------------------------
__global__ __launch_bounds__(256) void transpose_f32_bf16_k(
    const float* __restrict__ in, __bf16* __restrict__ out, long inRow, long outRow)
{
  const long tr = (long)blockIdx.y * 64;
  const long tc = (long)blockIdx.x * 64;
  __shared__ float tile[64][65];
  const int tid = threadIdx.x;
  const int rr = tid >> 4, c4 = (tid & 15) * 4;
#pragma unroll
  for (int p = 0; p < 4; p++) {
    const int r = p * 16 + rr;
    float4 v = *(const float4*)(in + (tr + r) * inRow + tc + c4);
    tile[r][c4]     = v.x;
    tile[r][c4 + 1] = v.y;
    tile[r][c4 + 2] = v.z;
    tile[r][c4 + 3] = v.w;
  }
  __syncthreads();
#pragma unroll
  for (int p = 0; p < 2; p++) {
    const int u  = p * 256 + tid;
    const int oc = u >> 3, ch = (u & 7) * 8;
    unsigned short e[8];
#pragma unroll
    for (int j = 0; j < 8; j++) {
      __bf16 b = (__bf16)tile[ch + j][oc];
      e[j] = *(unsigned short*)&b;
    }
    *(uint4*)(out + (tc + oc) * outRow + tr + ch) = *(const uint4*)e;
  }
}

// ---------------------------------------------------------------------------
// bf16 transpose with slices (V relayout): out[c][r] = in[r][c].
// ---------------------------------------------------------------------------
__global__ __launch_bounds__(256) void transpose_bf16_k(
    const __bf16* __restrict__ in, __bf16* __restrict__ out,
    long inRow, long outRow,
    int sliceDiv, long sliceOuter, long sliceInner, long outSlice)
{
  const int s = blockIdx.z;
  const __bf16* ip = in + (long)(s / sliceDiv) * sliceOuter + (long)(s % sliceDiv) * sliceInner;
  __bf16* op = out + (long)s * outSlice;
  const long tr = (long)blockIdx.y * 64;
  const long tc = (long)blockIdx.x * 64;
  __shared__ unsigned short tile[64][66];
  const int tid = threadIdx.x;
  const int rr  = tid >> 3;
  const int c8  = (tid & 7) * 8;
#pragma unroll
  for (int p = 0; p < 2; p++) {
    const int r = p * 32 + rr;
    uint4 v = *(const uint4*)(ip + (tr + r) * inRow + tc + c8);
    const unsigned short* e = (const unsigned short*)&v;
#pragma unroll
    for (int j = 0; j < 8; j++) tile[r][c8 + j] = e[j];
  }
  __syncthreads();
#pragma unroll
  for (int p = 0; p < 2; p++) {
    const int c = p * 32 + rr;
    unsigned short e[8];
#pragma unroll
    for (int j = 0; j < 8; j++) e[j] = tile[c8 + j][c];
    *(uint4*)(op + (tc + c) * outRow + tr + c8) = *(const uint4*)e;
  }
}

// ---------------------------------------------------------------------------
// GEMM: C[M][N] = A[M][K] * BT[N][K]^T, bf16 in, fp32 accum, OutT out.
// 256M x (NR*64)N tile, BK=64, 8 waves (2M x 4N), 512 threads, swizzled LDS.
// 4 phases per K-tile, counted-vmcnt pipeline, setprio around MFMA clusters.
// ---------------------------------------------------------------------------
template <typename OutT, int NR>
__global__ __launch_bounds__(512, 2) void gemm256(
    const __bf16* __restrict__ A, const __bf16* __restrict__ BT,
    OutT* __restrict__ C, int M, int N, int K)
{
  constexpr int BN   = NR * 64;       // block N-tile (192 or 256)
  constexpr int NB   = NR;            // B load-sets per K-tile (64 rows each)
  constexpr int ABUF = 256 * 64;      // elems per A buffer
  constexpr int BBUF = BN * 64;       // elems per B buffer
  const int n0   = blockIdx.x * BN;
  const int m0   = blockIdx.y * 256;
  const int tid  = threadIdx.x;
  const int lane = tid & 63;
  const int wave = tid >> 6;
  const int quad = lane >> 4;
  const int r    = lane & 15;
  const int wm   = wave >> 2;     // 0..1 : 128 M-rows per wave
  const int wn   = wave & 3;      // 0..3 : NR*16 N-cols per wave

  __shared__ __bf16 a_sm[2 * ABUF];   // [buf][row][chunk ^ (row&7)], chunks of 8
  __shared__ __bf16 b_sm[2 * BBUF];

  f32x4 acc[8][NR] = {};

  // staging: set si covers rows si*64 + (tid>>3), chunk tid&7 (swizzled src)
  const int srow = tid >> 3;                       // 0..63
  const int schk = ((tid & 7) ^ (srow & 7)) * 8;   // swizzled source chunk (elems)
  const __bf16* aSrc = A  + (size_t)(m0 + srow) * K + schk;
  const __bf16* bSrc = BT + (size_t)(n0 + srow) * K + schk;
  const size_t rstep = (size_t)64 * K;             // 64 rows of source
  const int wofs = wave * 512;                     // wave-uniform LDS dest base (elems)
  const int NT = K >> 6;

  auto stageA = [&](int si, int ko, int dstbuf) {
    __builtin_amdgcn_global_load_lds(AS1CV(aSrc + si * rstep + ko),
                                     AS3V(a_sm + dstbuf + si * 4096 + wofs), 16, 0, 0);
  };
  auto stageB = [&](int si, int ko, int dstbuf) {
    __builtin_amdgcn_global_load_lds(AS1CV(bSrc + si * rstep + ko),
                                     AS3V(b_sm + dstbuf + si * 4096 + wofs), 16, 0, 0);
  };

  // ---- prologue: stage tile 0 -> buf 0 (same issue order as the loop)
#pragma unroll
  for (int si = 0; si < NB; si++) stageB(si, 0, 0);
  stageA(0, 0, 0); stageA(2, 0, 0); stageA(1, 0, 0); stageA(3, 0, 0);
  asm volatile("s_waitcnt vmcnt(2)" ::: "memory");   // A1,A3 stay in flight
  __builtin_amdgcn_sched_barrier(0);
  __builtin_amdgcn_s_barrier();

#pragma unroll 2
  for (int t = 0; t < NT; ++t) {
    const int abuf = (t & 1) ? ABUF : 0;
    const int bbuf = (t & 1) ? BBUF : 0;
    const int anb  = abuf ^ ABUF;
    const int bnb  = bbuf ^ BBUF;
    const int kn   = ((t + 1 < NT) ? (t + 1) : t) * 64;   // clamped prefetch K offset
    const __bf16* as = a_sm + abuf + (wm * 128 + r) * 64;
    const __bf16* bs = b_sm + bbuf + (wn * (NR * 16) + r) * 64;
    bf16x8 bfr[NR][2];

#pragma unroll
    for (int p = 0; p < 4; p++) {
      // ---- LDS reads for this phase (latency overlaps the barrier below)
      if (p == 0) {
#pragma unroll
        for (int ni = 0; ni < NR; ni++)
#pragma unroll
          for (int kk = 0; kk < 2; kk++)
            bfr[ni][kk] = *(const bf16x8*)(bs + ni * 1024 + (((kk * 4 + quad) ^ (r & 7)) * 8));
      }
      bf16x8 af[2][2];
#pragma unroll
      for (int u = 0; u < 2; u++)
#pragma unroll
        for (int kk = 0; kk < 2; kk++)
          af[u][kk] = *(const bf16x8*)(as + (p * 2 + u) * 1024 + (((kk * 4 + quad) ^ (r & 7)) * 8));

      // ---- prefetch issues for tile t+1 (other buffer; no intra-tile hazard)
      if (p == 0) { stageB(0, kn, bnb); stageB(1, kn, bnb); }
      if (p == 1) {
        if constexpr (NR == 3) { stageB(2, kn, bnb); stageA(0, kn, anb); }
        else                   { stageB(2, kn, bnb); stageB(3, kn, bnb); }
      }
      if (p == 2) {
        if constexpr (NR == 3) { stageA(2, kn, anb); stageA(1, kn, anb); }
        else                   { stageA(0, kn, anb); stageA(2, kn, anb); }
      }
      if (p == 3) {
        if constexpr (NR == 3) { stageA(3, kn, anb); }
        else                   { stageA(1, kn, anb); stageA(3, kn, anb); }
      }

      __builtin_amdgcn_s_barrier();
      __builtin_amdgcn_s_setprio(1);
#pragma unroll
      for (int u = 0; u < 2; u++)
#pragma unroll
        for (int ni = 0; ni < NR; ni++)
#pragma unroll
          for (int kk = 0; kk < 2; kk++)
            acc[p * 2 + u][ni] = __builtin_amdgcn_mfma_f32_16x16x32_bf16(af[u][kk], bfr[ni][kk], acc[p * 2 + u][ni], 0, 0, 0);
      __builtin_amdgcn_s_setprio(0);
      if (p == 1) { asm volatile("s_waitcnt vmcnt(4)" ::: "memory"); __builtin_amdgcn_sched_barrier(0); }
      if (p == 3) { asm volatile("s_waitcnt vmcnt(2)" ::: "memory"); __builtin_amdgcn_sched_barrier(0); }
      __builtin_amdgcn_s_barrier();
    }
  }
  asm volatile("s_waitcnt vmcnt(0)" ::: "memory");     // drain tail loads before LDS dealloc

  // C/D layout: col = lane&15, row = quad*4 + reg
#pragma unroll
  for (int mi = 0; mi < 8; mi++)
#pragma unroll
    for (int ni = 0; ni < NR; ni++) {
      const int col = n0 + wn * (NR * 16) + ni * 16 + r;
#pragma unroll
      for (int g = 0; g < 4; g++) {
        const int row = m0 + wm * 128 + mi * 16 + quad * 4 + g;
        C[(size_t)row * N + col] = (OutT)acc[mi][ni][g];
      }
    }
}

// ---------------------------------------------------------------------------
// RoPE + relayout: qkv[B*T][6144](bf16) -> qr[B][H][T][D], kr[B][KV][T][D]
// ---------------------------------------------------------------------------
__global__ __launch_bounds__(256) void rope_k(
    const __bf16* __restrict__ qkv, __bf16* __restrict__ qr, __bf16* __restrict__ kr)
{
  const int m = blockIdx.x;
  const int b = m >> 11;
  const int t = m & 2047;
  const __bf16* rowp = qkv + (size_t)m * 6144;
  for (int n = threadIdx.x; n < 5120; n += 256) {
    const bool isq  = n < 4096;
    const int local = isq ? n : (n - 4096);
    const int head  = local >> 7;
    const int d     = local & 127;
    const int j     = d & 63;
    const float ex   = (float)(2 * j) / 128.0f;
    const float invf = 1.0f / powf(10000.0f, ex);
    const float ang  = ((float)t * invf) * 2.0f;   // * B=2 per reference quirk
    const float c = cosf(ang), s = sinf(ang);
    const float v0 = (float)rowp[n];
    const float v1 = (float)rowp[n + ((d < 64) ? 64 : -64)];
    const float o  = (d < 64) ? (v0 * c - v1 * s) : (v0 * c + v1 * s);
    if (isq) qr[((size_t)(b * 32 + head) * 2048 + t) * 128 + d] = (__bf16)o;
    else     kr[((size_t)(b * 8  + head) * 2048 + t) * 128 + d] = (__bf16)o;
  }
}

// ---------------------------------------------------------------------------
// Flash attention v2: S^T orientation, Q in registers, XOR-swizzled LDS,
// single-buffer K/V staged via global_load_lds (round-1 verified structure),
// alpha/l broadcast via __shfl (no LDS) -> LDS = 40960 B -> 4 blocks/CU.
// setprio(1) around both MFMA clusters.
// qr[B][H][T][D], kr[B][KV][T][D], vT[B][KV][D][T] -> y[B][T][H*D] (bf16)
// grid = (T/64, B*H); wave w owns q-rows [16w,16w+16).
// ---------------------------------------------------------------------------
__global__ __launch_bounds__(256, 4) void flash_k(
    const __bf16* __restrict__ qr, const __bf16* __restrict__ kr,
    const __bf16* __restrict__ vT, __bf16* __restrict__ y)
{
  const int qt  = (int)gridDim.x - 1 - (int)blockIdx.x;  // longest blocks first
  const int bh  = blockIdx.y;
  const int b   = bh >> 5;
  const int h   = bh & 31;
  const int kvh = h >> 2;
  const int tq0 = qt * 64;
  const int tid  = threadIdx.x;
  const int lane = tid & 63;
  const int wave = tid >> 6;
  const int quad = lane >> 4;
  const int r    = lane & 15;

  __shared__ __bf16 k_sm[64 * 128];     // [kv][d], chunk^=(row&15)   16 KiB
  __shared__ __bf16 v_sm[128 * 64];     // [d][t],  chunk^=(row&7)    16 KiB
  __shared__ __bf16 p_sm[4][16 * 64];   // per-wave [q][kv], chunk^=(q&7) 8 KiB

  const __bf16* kbase = kr + ((size_t)(b * 8 + kvh) * 2048) * 128;
  const __bf16* vbase = vT + ((size_t)(b * 8 + kvh) * 128) * 2048;

  // Q fragments in registers (B-operand layout): Q[q=wave*16+r][kk*32+quad*8+j]
  bf16x8 qf[4];
  {
    const __bf16* qrow = qr + ((size_t)(b * 32 + h) * 2048 + tq0 + wave * 16 + r) * 128;
#pragma unroll
    for (int kk = 0; kk < 4; kk++)
      qf[kk] = *(const bf16x8*)(qrow + kk * 32 + quad * 8);
  }

  f32x4 Oacc[8] = {};
  float mstate = -1e30f, lstate = 0.0f;
  const float scale = 0.08838834764831845f;   // 1/sqrt(128)

  const int rowK = lane >> 4, cK = lane & 15;   // K staging: 4 rows x 16 chunks
  const int rowV = lane >> 3, cV = lane & 7;    // V staging: 8 rows x 8 chunks

  for (int jt = 0; jt <= qt; jt++) {
    __syncthreads();   // prev iter's k/v reads complete
#pragma unroll
    for (int i = 0; i < 4; i++) {
      const int li = wave * 4 + i;
      {
        const int row = li * 4 + rowK;
        const __bf16* g = kbase + (size_t)(jt * 64 + row) * 128 + ((cK ^ (row & 15)) * 8);
        __builtin_amdgcn_global_load_lds(AS1CV(g), AS3V(k_sm + li * 512), 16, 0, 0);
      }
      {
        const int row = li * 8 + rowV;
        const __bf16* g = vbase + (size_t)row * 2048 + jt * 64 + ((cV ^ (row & 7)) * 8);
        __builtin_amdgcn_global_load_lds(AS1CV(g), AS3V(v_sm + li * 512), 16, 0, 0);
      }
    }
    __syncthreads();   // staging visible (compiler drains vmcnt before barrier)

    // S^T = K·Q^T : lane holds S[kv=mi*16+quad*4+g][q=wave*16+r]
    f32x4 St[4] = {};
    __builtin_amdgcn_s_setprio(1);
#pragma unroll
    for (int kk = 0; kk < 4; kk++)
#pragma unroll
      for (int mi = 0; mi < 4; mi++) {
        bf16x8 kf = *(const bf16x8*)(k_sm + (mi * 16 + r) * 128 + (((kk * 4 + quad) ^ r) * 8));
        St[mi] = __builtin_amdgcn_mfma_f32_16x16x32_bf16(kf, qf[kk], St[mi], 0, 0, 0);
      }
    __builtin_amdgcn_s_setprio(0);

    // online softmax: full row (64 kv) = 16 in-lane values + 4 quads
    const bool diag = (jt == qt);
    const int qabs  = tq0 + wave * 16 + r;
    float p[16];
#pragma unroll
    for (int mi = 0; mi < 4; mi++)
#pragma unroll
      for (int g = 0; g < 4; g++) {
        float v = St[mi][g] * scale;
        if (diag && (jt * 64 + mi * 16 + quad * 4 + g) > qabs) v = -3.0e38f;
        p[mi * 4 + g] = v;
      }
    float mx = p[0];
#pragma unroll
    for (int i = 1; i < 16; i++) mx = fmaxf(mx, p[i]);
    mx = fmaxf(mx, __shfl_xor(mx, 16));
    mx = fmaxf(mx, __shfl_xor(mx, 32));
    const float mnew  = fmaxf(mstate, mx);
    const float alpha = __expf(mstate - mnew);
    mstate = mnew;
    float rs = 0.0f;
#pragma unroll
    for (int i = 0; i < 16; i++) { p[i] = __expf(p[i] - mnew); rs += p[i]; }
    rs += __shfl_xor(rs, 16);
    rs += __shfl_xor(rs, 32);
    lstate = lstate * alpha + rs;

    // P -> p_sm (swizzled [q][kv]): kv = mi*16+quad*4+g, chunk cw = mi*2+(quad>>1)
#pragma unroll
    for (int mi = 0; mi < 4; mi++) {
      bf16x4 pk = { (__bf16)p[mi*4+0], (__bf16)p[mi*4+1], (__bf16)p[mi*4+2], (__bf16)p[mi*4+3] };
      const int cw = mi * 2 + (quad >> 1);
      *(bf16x4*)(&p_sm[wave][r * 64 + ((cw ^ (r & 7)) * 8) + (quad & 1) * 4]) = pk;
    }
    LGKM0();   // wave-private LDS ordering (write -> read below)

    // O rescale: alpha is quad-replicated per q-row -> fetch rows quad*4+g via shfl
    {
      const float a0 = __shfl(alpha, quad * 4 + 0);
      const float a1 = __shfl(alpha, quad * 4 + 1);
      const float a2 = __shfl(alpha, quad * 4 + 2);
      const float a3 = __shfl(alpha, quad * 4 + 3);
#pragma unroll
      for (int dt = 0; dt < 8; dt++) {
        Oacc[dt][0] *= a0; Oacc[dt][1] *= a1; Oacc[dt][2] *= a2; Oacc[dt][3] *= a3;
      }
    }

    // O += P·V  (A = P[q][kv] from p_sm, B = V^T[d][kv] from v_sm)
    __builtin_amdgcn_s_setprio(1);
#pragma unroll
    for (int kk = 0; kk < 2; kk++) {
      bf16x8 pf = *(const bf16x8*)(&p_sm[wave][r * 64 + (((kk * 4 + quad) ^ (r & 7)) * 8)]);
#pragma unroll
      for (int dt = 0; dt < 8; dt++) {
        bf16x8 vf = *(const bf16x8*)(v_sm + (dt * 16 + r) * 64 + (((kk * 4 + quad) ^ (r & 7)) * 8));
        Oacc[dt] = __builtin_amdgcn_mfma_f32_16x16x32_bf16(pf, vf, Oacc[dt], 0, 0, 0);
      }
    }
    __builtin_amdgcn_s_setprio(0);
  }

  // epilogue: l broadcast via shfl (lstate quad-replicated per q-row)
  const float il0 = 1.0f / __shfl(lstate, quad * 4 + 0);
  const float il1 = 1.0f / __shfl(lstate, quad * 4 + 1);
  const float il2 = 1.0f / __shfl(lstate, quad * 4 + 2);
  const float il3 = 1.0f / __shfl(lstate, quad * 4 + 3);
#pragma unroll
  for (int dt = 0; dt < 8; dt++) {
    const int col = h * 128 + dt * 16 + r;
    const int row = tq0 + wave * 16 + quad * 4;
    y[((size_t)(b * 2048 + row + 0)) * 4096 + col] = (__bf16)(Oacc[dt][0] * il0);
    y[((size_t)(b * 2048 + row + 1)) * 4096 + col] = (__bf16)(Oacc[dt][1] * il1);
    y[((size_t)(b * 2048 + row + 2)) * 4096 + col] = (__bf16)(Oacc[dt][2] * il2);
    y[((size_t)(b * 2048 + row + 3)) * 4096 + col] = (__bf16)(Oacc[dt][3] * il3);
  }
}

// ---------------------------------------------------------------------------
extern "C" void kernel_launch(void* const* d_in, const int* in_sizes, int n_in,
                              void* d_out, int out_size, void* d_ws, size_t ws_size,
                              hipStream_t stream)
{
  const float* x  = (const float*)d_in[0];
  // d_in[1] = mask (pure causal triu -> analytic)
  const float* wq = (const float*)d_in[2];
  const float* wk = (const float*)d_in[3];
  const float* wv = (const float*)d_in[4];
  const float* wo = (const float*)d_in[5];
  float* out = (float*)d_out;

  __bf16* ws  = (__bf16*)d_ws;
  __bf16* xb  = ws;                         // [4096][4096]
  __bf16* wT  = xb  + (size_t)16777216;     // [6144][4096]
  __bf16* qkv = wT  + (size_t)25165824;     // [4096][6144]
  __bf16* qr  = qkv + (size_t)25165824;     // [2][32][2048][128]
  __bf16* kr  = qr  + (size_t)16777216;     // [2][8][2048][128]
  __bf16* vT  = kr  + (size_t)4194304;      // [2][8][128][2048]
  __bf16* y   = xb;                         // alias: xb dead after gemm1
  __bf16* woT = wT;                         // alias: wT dead after gemm1

  dim3 blk(256);
  convert_k<<<dim3(16384), blk, 0, stream>>>(x, xb, 16777216L);
  transpose_f32_bf16_k<<<dim3(64, 64), blk, 0, stream>>>(wq, wT,                     4096L, 4096L);
  transpose_f32_bf16_k<<<dim3(16, 64), blk, 0, stream>>>(wk, wT + (size_t)4096*4096, 1024L, 4096L);
  transpose_f32_bf16_k<<<dim3(16, 64), blk, 0, stream>>>(wv, wT + (size_t)5120*4096, 1024L, 4096L);
  gemm256<__bf16, 3><<<dim3(32, 16), dim3(512), 0, stream>>>(xb, wT, qkv, 4096, 6144, 4096);
  transpose_f32_bf16_k<<<dim3(64, 64), blk, 0, stream>>>(wo, woT, 4096L, 4096L);
  rope_k<<<dim3(4096), blk, 0, stream>>>(qkv, qr, kr);
  transpose_bf16_k<<<dim3(2, 32, 16), blk, 0, stream>>>(qkv + 5120, vT, 6144L, 2048L,
                                                        8, (long)2048 * 6144, 128L, (long)128 * 2048);
  flash_k<<<dim3(32, 64), blk, 0, stream>>>(qr, kr, vT, y);
  gemm256<float, 4><<<dim3(16, 16), dim3(512), 0, stream>>>(y, woT, out, 4096, 4096, 4096);
}

// Round 8
// 746.824 us; speedup vs baseline: 1.6060x; 1.1100x over previous
//
#include <hip/hip_runtime.h>
#include <cstdint>
#include <cstddef>

typedef float  f32x4  __attribute__((ext_vector_type(4)));
typedef __bf16 bf16x8 __attribute__((ext_vector_type(8)));
typedef __bf16 bf16x4 __attribute__((ext_vector_type(4)));

// LDS aperture: low 32 bits of a flat shared pointer are the LDS offset.
#define AS1CV(p) ((const __attribute__((address_space(1))) void*)(uintptr_t)(p))
#define AS3V(p)  ((__attribute__((address_space(3))) void*)(uintptr_t)(p))
// wave-private LDS round-trip ordering (no cross-wave dependency -> no barrier)
#define LGKM0()  asm volatile("s_waitcnt lgkmcnt(0)" ::: "memory")

// ---------------------------------------------------------------------------
// fp32 -> bf16 convert (x).
// ---------------------------------------------------------------------------
__global__ __launch_bounds__(256) void convert_k(
    const float* __restrict__ in, __bf16* __restrict__ out, long n)
{
  const long i = ((long)blockIdx.x * 256 + threadIdx.x) * 4;
  if (i + 3 < n) {
    float4 v = *(const float4*)(in + i);
    __bf16 e[4] = { (__bf16)v.x, (__bf16)v.y, (__bf16)v.z, (__bf16)v.w };
    *(uint2*)(out + i) = *(const uint2*)e;
  }
}

// ---------------------------------------------------------------------------
// Weight transpose + convert: out_bf16[c][r] = (bf16)in_f32[r][c].
// ---------------------------------------------------------------------------
__global__ __launch_bounds__(256) void transpose_f32_bf16_k(
    const float* __restrict__ in, __bf16* __restrict__ out, long inRow, long outRow)
{
  const long tr = (long)blockIdx.y * 64;
  const long tc = (long)blockIdx.x * 64;
  __shared__ float tile[64][65];
  const int tid = threadIdx.x;
  const int rr = tid >> 4, c4 = (tid & 15) * 4;
#pragma unroll
  for (int p = 0; p < 4; p++) {
    const int r = p * 16 + rr;
    float4 v = *(const float4*)(in + (tr + r) * inRow + tc + c4);
    tile[r][c4]     = v.x;
    tile[r][c4 + 1] = v.y;
    tile[r][c4 + 2] = v.z;
    tile[r][c4 + 3] = v.w;
  }
  __syncthreads();
#pragma unroll
  for (int p = 0; p < 2; p++) {
    const int u  = p * 256 + tid;
    const int oc = u >> 3, ch = (u & 7) * 8;
    unsigned short e[8];
#pragma unroll
    for (int j = 0; j < 8; j++) {
      __bf16 b = (__bf16)tile[ch + j][oc];
      e[j] = *(unsigned short*)&b;
    }
    *(uint4*)(out + (tc + oc) * outRow + tr + ch) = *(const uint4*)e;
  }
}

// ---------------------------------------------------------------------------
// bf16 transpose with slices (V relayout): out[c][r] = in[r][c].
// ---------------------------------------------------------------------------
__global__ __launch_bounds__(256) void transpose_bf16_k(
    const __bf16* __restrict__ in, __bf16* __restrict__ out,
    long inRow, long outRow,
    int sliceDiv, long sliceOuter, long sliceInner, long outSlice)
{
  const int s = blockIdx.z;
  const __bf16* ip = in + (long)(s / sliceDiv) * sliceOuter + (long)(s % sliceDiv) * sliceInner;
  __bf16* op = out + (long)s * outSlice;
  const long tr = (long)blockIdx.y * 64;
  const long tc = (long)blockIdx.x * 64;
  __shared__ unsigned short tile[64][66];
  const int tid = threadIdx.x;
  const int rr  = tid >> 3;
  const int c8  = (tid & 7) * 8;
#pragma unroll
  for (int p = 0; p < 2; p++) {
    const int r = p * 32 + rr;
    uint4 v = *(const uint4*)(ip + (tr + r) * inRow + tc + c8);
    const unsigned short* e = (const unsigned short*)&v;
#pragma unroll
    for (int j = 0; j < 8; j++) tile[r][c8 + j] = e[j];
  }
  __syncthreads();
#pragma unroll
  for (int p = 0; p < 2; p++) {
    const int c = p * 32 + rr;
    unsigned short e[8];
#pragma unroll
    for (int j = 0; j < 8; j++) e[j] = tile[c8 + j][c];
    *(uint4*)(op + (tc + c) * outRow + tr + c8) = *(const uint4*)e;
  }
}

// ---------------------------------------------------------------------------
// GEMM: C[M][N] = A[M][K] * BT[N][K]^T, bf16 in, fp32 accum, OutT out.
// 256M x (NR*64)N tile, BK=64, 8 waves (2M x 4N), 512 threads, swizzled LDS.
// 4 phases per K-tile, counted-vmcnt pipeline, setprio around MFMA clusters.
// ---------------------------------------------------------------------------
template <typename OutT, int NR>
__global__ __launch_bounds__(512, 2) void gemm256(
    const __bf16* __restrict__ A, const __bf16* __restrict__ BT,
    OutT* __restrict__ C, int M, int N, int K)
{
  constexpr int BN   = NR * 64;       // block N-tile (192 or 256)
  constexpr int NB   = NR;            // B load-sets per K-tile (64 rows each)
  constexpr int ABUF = 256 * 64;      // elems per A buffer
  constexpr int BBUF = BN * 64;       // elems per B buffer
  const int n0   = blockIdx.x * BN;
  const int m0   = blockIdx.y * 256;
  const int tid  = threadIdx.x;
  const int lane = tid & 63;
  const int wave = tid >> 6;
  const int quad = lane >> 4;
  const int r    = lane & 15;
  const int wm   = wave >> 2;     // 0..1 : 128 M-rows per wave
  const int wn   = wave & 3;      // 0..3 : NR*16 N-cols per wave

  __shared__ __bf16 a_sm[2 * ABUF];   // [buf][row][chunk ^ (row&7)], chunks of 8
  __shared__ __bf16 b_sm[2 * BBUF];

  f32x4 acc[8][NR] = {};

  // staging: set si covers rows si*64 + (tid>>3), chunk tid&7 (swizzled src)
  const int srow = tid >> 3;                       // 0..63
  const int schk = ((tid & 7) ^ (srow & 7)) * 8;   // swizzled source chunk (elems)
  const __bf16* aSrc = A  + (size_t)(m0 + srow) * K + schk;
  const __bf16* bSrc = BT + (size_t)(n0 + srow) * K + schk;
  const size_t rstep = (size_t)64 * K;             // 64 rows of source
  const int wofs = wave * 512;                     // wave-uniform LDS dest base (elems)
  const int NT = K >> 6;

  auto stageA = [&](int si, int ko, int dstbuf) {
    __builtin_amdgcn_global_load_lds(AS1CV(aSrc + si * rstep + ko),
                                     AS3V(a_sm + dstbuf + si * 4096 + wofs), 16, 0, 0);
  };
  auto stageB = [&](int si, int ko, int dstbuf) {
    __builtin_amdgcn_global_load_lds(AS1CV(bSrc + si * rstep + ko),
                                     AS3V(b_sm + dstbuf + si * 4096 + wofs), 16, 0, 0);
  };

  // ---- prologue: stage tile 0 -> buf 0 (same issue order as the loop)
#pragma unroll
  for (int si = 0; si < NB; si++) stageB(si, 0, 0);
  stageA(0, 0, 0); stageA(2, 0, 0); stageA(1, 0, 0); stageA(3, 0, 0);
  asm volatile("s_waitcnt vmcnt(2)" ::: "memory");   // A1,A3 stay in flight
  __builtin_amdgcn_sched_barrier(0);
  __builtin_amdgcn_s_barrier();

#pragma unroll 2
  for (int t = 0; t < NT; ++t) {
    const int abuf = (t & 1) ? ABUF : 0;
    const int bbuf = (t & 1) ? BBUF : 0;
    const int anb  = abuf ^ ABUF;
    const int bnb  = bbuf ^ BBUF;
    const int kn   = ((t + 1 < NT) ? (t + 1) : t) * 64;   // clamped prefetch K offset
    const __bf16* as = a_sm + abuf + (wm * 128 + r) * 64;
    const __bf16* bs = b_sm + bbuf + (wn * (NR * 16) + r) * 64;
    bf16x8 bfr[NR][2];

#pragma unroll
    for (int p = 0; p < 4; p++) {
      // ---- LDS reads for this phase (latency overlaps the barrier below)
      if (p == 0) {
#pragma unroll
        for (int ni = 0; ni < NR; ni++)
#pragma unroll
          for (int kk = 0; kk < 2; kk++)
            bfr[ni][kk] = *(const bf16x8*)(bs + ni * 1024 + (((kk * 4 + quad) ^ (r & 7)) * 8));
      }
      bf16x8 af[2][2];
#pragma unroll
      for (int u = 0; u < 2; u++)
#pragma unroll
        for (int kk = 0; kk < 2; kk++)
          af[u][kk] = *(const bf16x8*)(as + (p * 2 + u) * 1024 + (((kk * 4 + quad) ^ (r & 7)) * 8));

      // ---- prefetch issues for tile t+1 (other buffer; no intra-tile hazard)
      if (p == 0) { stageB(0, kn, bnb); stageB(1, kn, bnb); }
      if (p == 1) {
        if constexpr (NR == 3) { stageB(2, kn, bnb); stageA(0, kn, anb); }
        else                   { stageB(2, kn, bnb); stageB(3, kn, bnb); }
      }
      if (p == 2) {
        if constexpr (NR == 3) { stageA(2, kn, anb); stageA(1, kn, anb); }
        else                   { stageA(0, kn, anb); stageA(2, kn, anb); }
      }
      if (p == 3) {
        if constexpr (NR == 3) { stageA(3, kn, anb); }
        else                   { stageA(1, kn, anb); stageA(3, kn, anb); }
      }

      __builtin_amdgcn_s_barrier();
      __builtin_amdgcn_s_setprio(1);
#pragma unroll
      for (int u = 0; u < 2; u++)
#pragma unroll
        for (int ni = 0; ni < NR; ni++)
#pragma unroll
          for (int kk = 0; kk < 2; kk++)
            acc[p * 2 + u][ni] = __builtin_amdgcn_mfma_f32_16x16x32_bf16(af[u][kk], bfr[ni][kk], acc[p * 2 + u][ni], 0, 0, 0);
      __builtin_amdgcn_s_setprio(0);
      if (p == 1) { asm volatile("s_waitcnt vmcnt(4)" ::: "memory"); __builtin_amdgcn_sched_barrier(0); }
      if (p == 3) { asm volatile("s_waitcnt vmcnt(2)" ::: "memory"); __builtin_amdgcn_sched_barrier(0); }
      __builtin_amdgcn_s_barrier();
    }
  }
  asm volatile("s_waitcnt vmcnt(0)" ::: "memory");     // drain tail loads before LDS dealloc

  // C/D layout: col = lane&15, row = quad*4 + reg
#pragma unroll
  for (int mi = 0; mi < 8; mi++)
#pragma unroll
    for (int ni = 0; ni < NR; ni++) {
      const int col = n0 + wn * (NR * 16) + ni * 16 + r;
#pragma unroll
      for (int g = 0; g < 4; g++) {
        const int row = m0 + wm * 128 + mi * 16 + quad * 4 + g;
        C[(size_t)row * N + col] = (OutT)acc[mi][ni][g];
      }
    }
}

// ---------------------------------------------------------------------------
// RoPE + relayout: qkv[B*T][6144](bf16) -> qr[B][H][T][D], kr[B][KV][T][D].
// Trig-hoisted: angle depends only on (t, d&63); t is block-uniform, so each
// thread owns ONE feature dim d (tid&127) and computes cos/sin ONCE, then
// loops over 20 heads (half-block: heads 0..19 / 20..39; 32 q + 8 k).
// 20x fewer powf/cosf/sinf than per-element; loads/stores stay lane-d
// coalesced; math identical per element.
// ---------------------------------------------------------------------------
__global__ __launch_bounds__(256) void rope_k(
    const __bf16* __restrict__ qkv, __bf16* __restrict__ qr, __bf16* __restrict__ kr)
{
  const int m = blockIdx.x;
  const int b = m >> 11;
  const int t = m & 2047;
  const __bf16* rowp = qkv + (size_t)m * 6144;
  const int tid = threadIdx.x;
  const int d   = tid & 127;          // owned feature dim
  const int h0  = (tid >> 7) * 20;    // heads 0..19 or 20..39
  const int j   = d & 63;
  const float ex   = (float)(2 * j) / 128.0f;
  const float invf = 1.0f / powf(10000.0f, ex);
  const float ang  = ((float)t * invf) * 2.0f;   // * B=2 per reference quirk
  const float c = cosf(ang), s = sinf(ang);
  const int   dOff = (d < 64) ? 64 : -64;
  const float sgn  = (d < 64) ? -1.0f : 1.0f;
#pragma unroll
  for (int hh = 0; hh < 20; hh++) {
    const int head = h0 + hh;                    // 0..39 (wave-uniform)
    const int n = head * 128 + d;
    const float v0 = (float)rowp[n];
    const float v1 = (float)rowp[n + dOff];
    const float o  = v0 * c + sgn * (v1 * s);
    if (head < 32)
      qr[((size_t)(b * 32 + head) * 2048 + t) * 128 + d] = (__bf16)o;
    else
      kr[((size_t)(b * 8 + (head - 32)) * 2048 + t) * 128 + d] = (__bf16)o;
  }
}

// ---------------------------------------------------------------------------
// Flash attention v2 (round-4 measured version): S^T orientation, Q in regs,
// XOR-swizzled LDS, single-buffer K/V staged via global_load_lds,
// alpha/l broadcast via __shfl (no LDS) -> LDS = 40960 B -> 4 blocks/CU.
// setprio(1) around both MFMA clusters.
// qr[B][H][T][D], kr[B][KV][T][D], vT[B][KV][D][T] -> y[B][T][H*D] (bf16)
// grid = (T/64, B*H); wave w owns q-rows [16w,16w+16).
// ---------------------------------------------------------------------------
__global__ __launch_bounds__(256, 4) void flash_k(
    const __bf16* __restrict__ qr, const __bf16* __restrict__ kr,
    const __bf16* __restrict__ vT, __bf16* __restrict__ y)
{
  const int qt  = (int)gridDim.x - 1 - (int)blockIdx.x;  // longest blocks first
  const int bh  = blockIdx.y;
  const int b   = bh >> 5;
  const int h   = bh & 31;
  const int kvh = h >> 2;
  const int tq0 = qt * 64;
  const int tid  = threadIdx.x;
  const int lane = tid & 63;
  const int wave = tid >> 6;
  const int quad = lane >> 4;
  const int r    = lane & 15;

  __shared__ __bf16 k_sm[64 * 128];     // [kv][d], chunk^=(row&15)   16 KiB
  __shared__ __bf16 v_sm[128 * 64];     // [d][t],  chunk^=(row&7)    16 KiB
  __shared__ __bf16 p_sm[4][16 * 64];   // per-wave [q][kv], chunk^=(q&7) 8 KiB

  const __bf16* kbase = kr + ((size_t)(b * 8 + kvh) * 2048) * 128;
  const __bf16* vbase = vT + ((size_t)(b * 8 + kvh) * 128) * 2048;

  // Q fragments in registers (B-operand layout): Q[q=wave*16+r][kk*32+quad*8+j]
  bf16x8 qf[4];
  {
    const __bf16* qrow = qr + ((size_t)(b * 32 + h) * 2048 + tq0 + wave * 16 + r) * 128;
#pragma unroll
    for (int kk = 0; kk < 4; kk++)
      qf[kk] = *(const bf16x8*)(qrow + kk * 32 + quad * 8);
  }

  f32x4 Oacc[8] = {};
  float mstate = -1e30f, lstate = 0.0f;
  const float scale = 0.08838834764831845f;   // 1/sqrt(128)

  const int rowK = lane >> 4, cK = lane & 15;   // K staging: 4 rows x 16 chunks
  const int rowV = lane >> 3, cV = lane & 7;    // V staging: 8 rows x 8 chunks

  for (int jt = 0; jt <= qt; jt++) {
    __syncthreads();   // prev iter's k/v reads complete
#pragma unroll
    for (int i = 0; i < 4; i++) {
      const int li = wave * 4 + i;
      {
        const int row = li * 4 + rowK;
        const __bf16* g = kbase + (size_t)(jt * 64 + row) * 128 + ((cK ^ (row & 15)) * 8);
        __builtin_amdgcn_global_load_lds(AS1CV(g), AS3V(k_sm + li * 512), 16, 0, 0);
      }
      {
        const int row = li * 8 + rowV;
        const __bf16* g = vbase + (size_t)row * 2048 + jt * 64 + ((cV ^ (row & 7)) * 8);
        __builtin_amdgcn_global_load_lds(AS1CV(g), AS3V(v_sm + li * 512), 16, 0, 0);
      }
    }
    __syncthreads();   // staging visible (compiler drains vmcnt before barrier)

    // S^T = K·Q^T : lane holds S[kv=mi*16+quad*4+g][q=wave*16+r]
    f32x4 St[4] = {};
    __builtin_amdgcn_s_setprio(1);
#pragma unroll
    for (int kk = 0; kk < 4; kk++)
#pragma unroll
      for (int mi = 0; mi < 4; mi++) {
        bf16x8 kf = *(const bf16x8*)(k_sm + (mi * 16 + r) * 128 + (((kk * 4 + quad) ^ r) * 8));
        St[mi] = __builtin_amdgcn_mfma_f32_16x16x32_bf16(kf, qf[kk], St[mi], 0, 0, 0);
      }
    __builtin_amdgcn_s_setprio(0);

    // online softmax: full row (64 kv) = 16 in-lane values + 4 quads
    const bool diag = (jt == qt);
    const int qabs  = tq0 + wave * 16 + r;
    float p[16];
#pragma unroll
    for (int mi = 0; mi < 4; mi++)
#pragma unroll
      for (int g = 0; g < 4; g++) {
        float v = St[mi][g] * scale;
        if (diag && (jt * 64 + mi * 16 + quad * 4 + g) > qabs) v = -3.0e38f;
        p[mi * 4 + g] = v;
      }
    float mx = p[0];
#pragma unroll
    for (int i = 1; i < 16; i++) mx = fmaxf(mx, p[i]);
    mx = fmaxf(mx, __shfl_xor(mx, 16));
    mx = fmaxf(mx, __shfl_xor(mx, 32));
    const float mnew  = fmaxf(mstate, mx);
    const float alpha = __expf(mstate - mnew);
    mstate = mnew;
    float rs = 0.0f;
#pragma unroll
    for (int i = 0; i < 16; i++) { p[i] = __expf(p[i] - mnew); rs += p[i]; }
    rs += __shfl_xor(rs, 16);
    rs += __shfl_xor(rs, 32);
    lstate = lstate * alpha + rs;

    // P -> p_sm (swizzled [q][kv]): kv = mi*16+quad*4+g, chunk cw = mi*2+(quad>>1)
#pragma unroll
    for (int mi = 0; mi < 4; mi++) {
      bf16x4 pk = { (__bf16)p[mi*4+0], (__bf16)p[mi*4+1], (__bf16)p[mi*4+2], (__bf16)p[mi*4+3] };
      const int cw = mi * 2 + (quad >> 1);
      *(bf16x4*)(&p_sm[wave][r * 64 + ((cw ^ (r & 7)) * 8) + (quad & 1) * 4]) = pk;
    }
    LGKM0();   // wave-private LDS ordering (write -> read below)

    // O rescale: alpha is quad-replicated per q-row -> fetch rows quad*4+g via shfl
    {
      const float a0 = __shfl(alpha, quad * 4 + 0);
      const float a1 = __shfl(alpha, quad * 4 + 1);
      const float a2 = __shfl(alpha, quad * 4 + 2);
      const float a3 = __shfl(alpha, quad * 4 + 3);
#pragma unroll
      for (int dt = 0; dt < 8; dt++) {
        Oacc[dt][0] *= a0; Oacc[dt][1] *= a1; Oacc[dt][2] *= a2; Oacc[dt][3] *= a3;
      }
    }

    // O += P·V  (A = P[q][kv] from p_sm, B = V^T[d][kv] from v_sm)
    __builtin_amdgcn_s_setprio(1);
#pragma unroll
    for (int kk = 0; kk < 2; kk++) {
      bf16x8 pf = *(const bf16x8*)(&p_sm[wave][r * 64 + (((kk * 4 + quad) ^ (r & 7)) * 8)]);
#pragma unroll
      for (int dt = 0; dt < 8; dt++) {
        bf16x8 vf = *(const bf16x8*)(v_sm + (dt * 16 + r) * 64 + (((kk * 4 + quad) ^ (r & 7)) * 8));
        Oacc[dt] = __builtin_amdgcn_mfma_f32_16x16x32_bf16(pf, vf, Oacc[dt], 0, 0, 0);
      }
    }
    __builtin_amdgcn_s_setprio(0);
  }

  // epilogue: l broadcast via shfl (lstate quad-replicated per q-row)
  const float il0 = 1.0f / __shfl(lstate, quad * 4 + 0);
  const float il1 = 1.0f / __shfl(lstate, quad * 4 + 1);
  const float il2 = 1.0f / __shfl(lstate, quad * 4 + 2);
  const float il3 = 1.0f / __shfl(lstate, quad * 4 + 3);
#pragma unroll
  for (int dt = 0; dt < 8; dt++) {
    const int col = h * 128 + dt * 16 + r;
    const int row = tq0 + wave * 16 + quad * 4;
    y[((size_t)(b * 2048 + row + 0)) * 4096 + col] = (__bf16)(Oacc[dt][0] * il0);
    y[((size_t)(b * 2048 + row + 1)) * 4096 + col] = (__bf16)(Oacc[dt][1] * il1);
    y[((size_t)(b * 2048 + row + 2)) * 4096 + col] = (__bf16)(Oacc[dt][2] * il2);
    y[((size_t)(b * 2048 + row + 3)) * 4096 + col] = (__bf16)(Oacc[dt][3] * il3);
  }
}

// ---------------------------------------------------------------------------
extern "C" void kernel_launch(void* const* d_in, const int* in_sizes, int n_in,
                              void* d_out, int out_size, void* d_ws, size_t ws_size,
                              hipStream_t stream)
{
  const float* x  = (const float*)d_in[0];
  // d_in[1] = mask (pure causal triu -> analytic)
  const float* wq = (const float*)d_in[2];
  const float* wk = (const float*)d_in[3];
  const float* wv = (const float*)d_in[4];
  const float* wo = (const float*)d_in[5];
  float* out = (float*)d_out;

  __bf16* ws  = (__bf16*)d_ws;
  __bf16* xb  = ws;                         // [4096][4096]
  __bf16* wT  = xb  + (size_t)16777216;     // [6144][4096]
  __bf16* qkv = wT  + (size_t)25165824;     // [4096][6144]
  __bf16* qr  = qkv + (size_t)25165824;     // [2][32][2048][128]
  __bf16* kr  = qr  + (size_t)16777216;     // [2][8][2048][128]
  __bf16* vT  = kr  + (size_t)4194304;      // [2][8][128][2048]
  __bf16* y   = xb;                         // alias: xb dead after gemm1
  __bf16* woT = wT;                         // alias: wT dead after gemm1

  dim3 blk(256);
  convert_k<<<dim3(16384), blk, 0, stream>>>(x, xb, 16777216L);
  transpose_f32_bf16_k<<<dim3(64, 64), blk, 0, stream>>>(wq, wT,                     4096L, 4096L);
  transpose_f32_bf16_k<<<dim3(16, 64), blk, 0, stream>>>(wk, wT + (size_t)4096*4096, 1024L, 4096L);
  transpose_f32_bf16_k<<<dim3(16, 64), blk, 0, stream>>>(wv, wT + (size_t)5120*4096, 1024L, 4096L);
  gemm256<__bf16, 3><<<dim3(32, 16), dim3(512), 0, stream>>>(xb, wT, qkv, 4096, 6144, 4096);
  transpose_f32_bf16_k<<<dim3(64, 64), blk, 0, stream>>>(wo, woT, 4096L, 4096L);
  rope_k<<<dim3(4096), blk, 0, stream>>>(qkv, qr, kr);
  transpose_bf16_k<<<dim3(2, 32, 16), blk, 0, stream>>>(qkv + 5120, vT, 6144L, 2048L,
                                                        8, (long)2048 * 6144, 128L, (long)128 * 2048);
  flash_k<<<dim3(32, 64), blk, 0, stream>>>(qr, kr, vT, y);
  gemm256<float, 4><<<dim3(16, 16), dim3(512), 0, stream>>>(y, woT, out, 4096, 4096, 4096);
}

// Round 9
// 667.970 us; speedup vs baseline: 1.7955x; 1.1181x over previous
//
#include <hip/hip_runtime.h>
#include <cstdint>
#include <cstddef>

typedef float  f32x4  __attribute__((ext_vector_type(4)));
typedef __bf16 bf16x8 __attribute__((ext_vector_type(8)));
typedef __bf16 bf16x4 __attribute__((ext_vector_type(4)));

// LDS aperture: low 32 bits of a flat shared pointer are the LDS offset.
#define AS1CV(p) ((const __attribute__((address_space(1))) void*)(uintptr_t)(p))
#define AS3V(p)  ((__attribute__((address_space(3))) void*)(uintptr_t)(p))
// wave-private LDS round-trip ordering (no cross-wave dependency -> no barrier)
#define LGKM0()  asm volatile("s_waitcnt lgkmcnt(0)" ::: "memory")

// ---------------------------------------------------------------------------
// fp32 -> bf16 convert (x).
// ---------------------------------------------------------------------------
__global__ __launch_bounds__(256) void convert_k(
    const float* __restrict__ in, __bf16* __restrict__ out, long n)
{
  const long i = ((long)blockIdx.x * 256 + threadIdx.x) * 4;
  if (i + 3 < n) {
    float4 v = *(const float4*)(in + i);
    __bf16 e[4] = { (__bf16)v.x, (__bf16)v.y, (__bf16)v.z, (__bf16)v.w };
    *(uint2*)(out + i) = *(const uint2*)e;
  }
}

// ---------------------------------------------------------------------------
// Weight transpose + convert: out_bf16[c][r] = (bf16)in_f32[r][c].
// ---------------------------------------------------------------------------
__global__ __launch_bounds__(256) void transpose_f32_bf16_k(
    const float* __restrict__ in, __bf16* __restrict__ out, long inRow, long outRow)
{
  const long tr = (long)blockIdx.y * 64;
  const long tc = (long)blockIdx.x * 64;
  __shared__ float tile[64][65];
  const int tid = threadIdx.x;
  const int rr = tid >> 4, c4 = (tid & 15) * 4;
#pragma unroll
  for (int p = 0; p < 4; p++) {
    const int r = p * 16 + rr;
    float4 v = *(const float4*)(in + (tr + r) * inRow + tc + c4);
    tile[r][c4]     = v.x;
    tile[r][c4 + 1] = v.y;
    tile[r][c4 + 2] = v.z;
    tile[r][c4 + 3] = v.w;
  }
  __syncthreads();
#pragma unroll
  for (int p = 0; p < 2; p++) {
    const int u  = p * 256 + tid;
    const int oc = u >> 3, ch = (u & 7) * 8;
    unsigned short e[8];
#pragma unroll
    for (int j = 0; j < 8; j++) {
      __bf16 b = (__bf16)tile[ch + j][oc];
      e[j] = *(unsigned short*)&b;
    }
    *(uint4*)(out + (tc + oc) * outRow + tr + ch) = *(const uint4*)e;
  }
}

// ---------------------------------------------------------------------------
// bf16 transpose with slices (V relayout): out[c][r] = in[r][c].
// ---------------------------------------------------------------------------
__global__ __launch_bounds__(256) void transpose_bf16_k(
    const __bf16* __restrict__ in, __bf16* __restrict__ out,
    long inRow, long outRow,
    int sliceDiv, long sliceOuter, long sliceInner, long outSlice)
{
  const int s = blockIdx.z;
  const __bf16* ip = in + (long)(s / sliceDiv) * sliceOuter + (long)(s % sliceDiv) * sliceInner;
  __bf16* op = out + (long)s * outSlice;
  const long tr = (long)blockIdx.y * 64;
  const long tc = (long)blockIdx.x * 64;
  __shared__ unsigned short tile[64][66];
  const int tid = threadIdx.x;
  const int rr  = tid >> 3;
  const int c8  = (tid & 7) * 8;
#pragma unroll
  for (int p = 0; p < 2; p++) {
    const int r = p * 32 + rr;
    uint4 v = *(const uint4*)(ip + (tr + r) * inRow + tc + c8);
    const unsigned short* e = (const unsigned short*)&v;
#pragma unroll
    for (int j = 0; j < 8; j++) tile[r][c8 + j] = e[j];
  }
  __syncthreads();
#pragma unroll
  for (int p = 0; p < 2; p++) {
    const int c = p * 32 + rr;
    unsigned short e[8];
#pragma unroll
    for (int j = 0; j < 8; j++) e[j] = tile[c8 + j][c];
    *(uint4*)(op + (tc + c) * outRow + tr + c8) = *(const uint4*)e;
  }
}

// ---------------------------------------------------------------------------
// GEMM: C[M][N] = A[M][K] * BT[N][K]^T, bf16 in, fp32 accum, OutT out.
// 256M x (NR*64)N tile, BK=64, 8 waves (2M x 4N), 512 threads, swizzled LDS.
// 4 phases per K-tile, counted-vmcnt pipeline, setprio around MFMA clusters.
// ---------------------------------------------------------------------------
template <typename OutT, int NR>
__global__ __launch_bounds__(512, 2) void gemm256(
    const __bf16* __restrict__ A, const __bf16* __restrict__ BT,
    OutT* __restrict__ C, int M, int N, int K)
{
  constexpr int BN   = NR * 64;       // block N-tile (192 or 256)
  constexpr int NB   = NR;            // B load-sets per K-tile (64 rows each)
  constexpr int ABUF = 256 * 64;      // elems per A buffer
  constexpr int BBUF = BN * 64;       // elems per B buffer
  const int n0   = blockIdx.x * BN;
  const int m0   = blockIdx.y * 256;
  const int tid  = threadIdx.x;
  const int lane = tid & 63;
  const int wave = tid >> 6;
  const int quad = lane >> 4;
  const int r    = lane & 15;
  const int wm   = wave >> 2;     // 0..1 : 128 M-rows per wave
  const int wn   = wave & 3;      // 0..3 : NR*16 N-cols per wave

  __shared__ __bf16 a_sm[2 * ABUF];   // [buf][row][chunk ^ (row&7)], chunks of 8
  __shared__ __bf16 b_sm[2 * BBUF];

  f32x4 acc[8][NR] = {};

  // staging: set si covers rows si*64 + (tid>>3), chunk tid&7 (swizzled src)
  const int srow = tid >> 3;                       // 0..63
  const int schk = ((tid & 7) ^ (srow & 7)) * 8;   // swizzled source chunk (elems)
  const __bf16* aSrc = A  + (size_t)(m0 + srow) * K + schk;
  const __bf16* bSrc = BT + (size_t)(n0 + srow) * K + schk;
  const size_t rstep = (size_t)64 * K;             // 64 rows of source
  const int wofs = wave * 512;                     // wave-uniform LDS dest base (elems)
  const int NT = K >> 6;

  auto stageA = [&](int si, int ko, int dstbuf) {
    __builtin_amdgcn_global_load_lds(AS1CV(aSrc + si * rstep + ko),
                                     AS3V(a_sm + dstbuf + si * 4096 + wofs), 16, 0, 0);
  };
  auto stageB = [&](int si, int ko, int dstbuf) {
    __builtin_amdgcn_global_load_lds(AS1CV(bSrc + si * rstep + ko),
                                     AS3V(b_sm + dstbuf + si * 4096 + wofs), 16, 0, 0);
  };

  // ---- prologue: stage tile 0 -> buf 0 (same issue order as the loop)
#pragma unroll
  for (int si = 0; si < NB; si++) stageB(si, 0, 0);
  stageA(0, 0, 0); stageA(2, 0, 0); stageA(1, 0, 0); stageA(3, 0, 0);
  asm volatile("s_waitcnt vmcnt(2)" ::: "memory");   // A1,A3 stay in flight
  __builtin_amdgcn_sched_barrier(0);
  __builtin_amdgcn_s_barrier();

#pragma unroll 2
  for (int t = 0; t < NT; ++t) {
    const int abuf = (t & 1) ? ABUF : 0;
    const int bbuf = (t & 1) ? BBUF : 0;
    const int anb  = abuf ^ ABUF;
    const int bnb  = bbuf ^ BBUF;
    const int kn   = ((t + 1 < NT) ? (t + 1) : t) * 64;   // clamped prefetch K offset
    const __bf16* as = a_sm + abuf + (wm * 128 + r) * 64;
    const __bf16* bs = b_sm + bbuf + (wn * (NR * 16) + r) * 64;
    bf16x8 bfr[NR][2];

#pragma unroll
    for (int p = 0; p < 4; p++) {
      // ---- LDS reads for this phase (latency overlaps the barrier below)
      if (p == 0) {
#pragma unroll
        for (int ni = 0; ni < NR; ni++)
#pragma unroll
          for (int kk = 0; kk < 2; kk++)
            bfr[ni][kk] = *(const bf16x8*)(bs + ni * 1024 + (((kk * 4 + quad) ^ (r & 7)) * 8));
      }
      bf16x8 af[2][2];
#pragma unroll
      for (int u = 0; u < 2; u++)
#pragma unroll
        for (int kk = 0; kk < 2; kk++)
          af[u][kk] = *(const bf16x8*)(as + (p * 2 + u) * 1024 + (((kk * 4 + quad) ^ (r & 7)) * 8));

      // ---- prefetch issues for tile t+1 (other buffer; no intra-tile hazard)
      if (p == 0) { stageB(0, kn, bnb); stageB(1, kn, bnb); }
      if (p == 1) {
        if constexpr (NR == 3) { stageB(2, kn, bnb); stageA(0, kn, anb); }
        else                   { stageB(2, kn, bnb); stageB(3, kn, bnb); }
      }
      if (p == 2) {
        if constexpr (NR == 3) { stageA(2, kn, anb); stageA(1, kn, anb); }
        else                   { stageA(0, kn, anb); stageA(2, kn, anb); }
      }
      if (p == 3) {
        if constexpr (NR == 3) { stageA(3, kn, anb); }
        else                   { stageA(1, kn, anb); stageA(3, kn, anb); }
      }

      __builtin_amdgcn_s_barrier();
      __builtin_amdgcn_s_setprio(1);
#pragma unroll
      for (int u = 0; u < 2; u++)
#pragma unroll
        for (int ni = 0; ni < NR; ni++)
#pragma unroll
          for (int kk = 0; kk < 2; kk++)
            acc[p * 2 + u][ni] = __builtin_amdgcn_mfma_f32_16x16x32_bf16(af[u][kk], bfr[ni][kk], acc[p * 2 + u][ni], 0, 0, 0);
      __builtin_amdgcn_s_setprio(0);
      if (p == 1) { asm volatile("s_waitcnt vmcnt(4)" ::: "memory"); __builtin_amdgcn_sched_barrier(0); }
      if (p == 3) { asm volatile("s_waitcnt vmcnt(2)" ::: "memory"); __builtin_amdgcn_sched_barrier(0); }
      __builtin_amdgcn_s_barrier();
    }
  }
  asm volatile("s_waitcnt vmcnt(0)" ::: "memory");     // drain tail loads before LDS dealloc

  // C/D layout: col = lane&15, row = quad*4 + reg
#pragma unroll
  for (int mi = 0; mi < 8; mi++)
#pragma unroll
    for (int ni = 0; ni < NR; ni++) {
      const int col = n0 + wn * (NR * 16) + ni * 16 + r;
#pragma unroll
      for (int g = 0; g < 4; g++) {
        const int row = m0 + wm * 128 + mi * 16 + quad * 4 + g;
        C[(size_t)row * N + col] = (OutT)acc[mi][ni][g];
      }
    }
}

// ---------------------------------------------------------------------------
// RoPE + relayout: qkv[B*T][6144](bf16) -> qr[B][H][T][D], kr[B][KV][T][D].
// Trig-hoisted: angle depends only on (t, d&63); t is block-uniform, so each
// thread owns ONE feature dim d (tid&127) and computes cos/sin ONCE, then
// loops over 20 heads (half-block: heads 0..19 / 20..39; 32 q + 8 k).
// ---------------------------------------------------------------------------
__global__ __launch_bounds__(256) void rope_k(
    const __bf16* __restrict__ qkv, __bf16* __restrict__ qr, __bf16* __restrict__ kr)
{
  const int m = blockIdx.x;
  const int b = m >> 11;
  const int t = m & 2047;
  const __bf16* rowp = qkv + (size_t)m * 6144;
  const int tid = threadIdx.x;
  const int d   = tid & 127;          // owned feature dim
  const int h0  = (tid >> 7) * 20;    // heads 0..19 or 20..39
  const int j   = d & 63;
  const float ex   = (float)(2 * j) / 128.0f;
  const float invf = 1.0f / powf(10000.0f, ex);
  const float ang  = ((float)t * invf) * 2.0f;   // * B=2 per reference quirk
  const float c = cosf(ang), s = sinf(ang);
  const int   dOff = (d < 64) ? 64 : -64;
  const float sgn  = (d < 64) ? -1.0f : 1.0f;
#pragma unroll
  for (int hh = 0; hh < 20; hh++) {
    const int head = h0 + hh;                    // 0..39 (wave-uniform)
    const int n = head * 128 + d;
    const float v0 = (float)rowp[n];
    const float v1 = (float)rowp[n + dOff];
    const float o  = v0 * c + sgn * (v1 * s);
    if (head < 32)
      qr[((size_t)(b * 32 + head) * 2048 + t) * 128 + d] = (__bf16)o;
    else
      kr[((size_t)(b * 8 + (head - 32)) * 2048 + t) * 128 + d] = (__bf16)o;
  }
}

// ---------------------------------------------------------------------------
// Flash attention v2 (round-4 measured structure): S^T orientation, Q in regs,
// XOR-swizzled LDS, single-buffer K/V staged via global_load_lds,
// alpha/l broadcast via __shfl (no LDS) -> LDS = 40960 B -> 4 blocks/CU.
// setprio(1) around both MFMA clusters.
// GRID CHANGE: (x=bh, y=qt-tiles), qt = gridDim.y-1-blockIdx.y -> blocks are
// dispatched GLOBALLY longest-first (HW dispatches x-fastest); the old
// (x=qt, y=bh) order put bh=63's 32-iteration block nearly LAST, leaving a
// long single-block tail. Pure scheduling change, no math/sync change.
// qr[B][H][T][D], kr[B][KV][T][D], vT[B][KV][D][T] -> y[B][T][H*D] (bf16)
// ---------------------------------------------------------------------------
__global__ __launch_bounds__(256, 4) void flash_k(
    const __bf16* __restrict__ qr, const __bf16* __restrict__ kr,
    const __bf16* __restrict__ vT, __bf16* __restrict__ y)
{
  const int qt  = (int)gridDim.y - 1 - (int)blockIdx.y;  // global longest-first
  const int bh  = blockIdx.x;
  const int b   = bh >> 5;
  const int h   = bh & 31;
  const int kvh = h >> 2;
  const int tq0 = qt * 64;
  const int tid  = threadIdx.x;
  const int lane = tid & 63;
  const int wave = tid >> 6;
  const int quad = lane >> 4;
  const int r    = lane & 15;

  __shared__ __bf16 k_sm[64 * 128];     // [kv][d], chunk^=(row&15)   16 KiB
  __shared__ __bf16 v_sm[128 * 64];     // [d][t],  chunk^=(row&7)    16 KiB
  __shared__ __bf16 p_sm[4][16 * 64];   // per-wave [q][kv], chunk^=(q&7) 8 KiB

  const __bf16* kbase = kr + ((size_t)(b * 8 + kvh) * 2048) * 128;
  const __bf16* vbase = vT + ((size_t)(b * 8 + kvh) * 128) * 2048;

  // Q fragments in registers (B-operand layout): Q[q=wave*16+r][kk*32+quad*8+j]
  bf16x8 qf[4];
  {
    const __bf16* qrow = qr + ((size_t)(b * 32 + h) * 2048 + tq0 + wave * 16 + r) * 128;
#pragma unroll
    for (int kk = 0; kk < 4; kk++)
      qf[kk] = *(const bf16x8*)(qrow + kk * 32 + quad * 8);
  }

  f32x4 Oacc[8] = {};
  float mstate = -1e30f, lstate = 0.0f;
  const float scale = 0.08838834764831845f;   // 1/sqrt(128)

  const int rowK = lane >> 4, cK = lane & 15;   // K staging: 4 rows x 16 chunks
  const int rowV = lane >> 3, cV = lane & 7;    // V staging: 8 rows x 8 chunks

  for (int jt = 0; jt <= qt; jt++) {
    __syncthreads();   // prev iter's k/v reads complete
#pragma unroll
    for (int i = 0; i < 4; i++) {
      const int li = wave * 4 + i;
      {
        const int row = li * 4 + rowK;
        const __bf16* g = kbase + (size_t)(jt * 64 + row) * 128 + ((cK ^ (row & 15)) * 8);
        __builtin_amdgcn_global_load_lds(AS1CV(g), AS3V(k_sm + li * 512), 16, 0, 0);
      }
      {
        const int row = li * 8 + rowV;
        const __bf16* g = vbase + (size_t)row * 2048 + jt * 64 + ((cV ^ (row & 7)) * 8);
        __builtin_amdgcn_global_load_lds(AS1CV(g), AS3V(v_sm + li * 512), 16, 0, 0);
      }
    }
    __syncthreads();   // staging visible (compiler drains vmcnt before barrier)

    // S^T = K·Q^T : lane holds S[kv=mi*16+quad*4+g][q=wave*16+r]
    f32x4 St[4] = {};
    __builtin_amdgcn_s_setprio(1);
#pragma unroll
    for (int kk = 0; kk < 4; kk++)
#pragma unroll
      for (int mi = 0; mi < 4; mi++) {
        bf16x8 kf = *(const bf16x8*)(k_sm + (mi * 16 + r) * 128 + (((kk * 4 + quad) ^ r) * 8));
        St[mi] = __builtin_amdgcn_mfma_f32_16x16x32_bf16(kf, qf[kk], St[mi], 0, 0, 0);
      }
    __builtin_amdgcn_s_setprio(0);

    // online softmax: full row (64 kv) = 16 in-lane values + 4 quads
    const bool diag = (jt == qt);
    const int qabs  = tq0 + wave * 16 + r;
    float p[16];
#pragma unroll
    for (int mi = 0; mi < 4; mi++)
#pragma unroll
      for (int g = 0; g < 4; g++) {
        float v = St[mi][g] * scale;
        if (diag && (jt * 64 + mi * 16 + quad * 4 + g) > qabs) v = -3.0e38f;
        p[mi * 4 + g] = v;
      }
    float mx = p[0];
#pragma unroll
    for (int i = 1; i < 16; i++) mx = fmaxf(mx, p[i]);
    mx = fmaxf(mx, __shfl_xor(mx, 16));
    mx = fmaxf(mx, __shfl_xor(mx, 32));
    const float mnew  = fmaxf(mstate, mx);
    const float alpha = __expf(mstate - mnew);
    mstate = mnew;
    float rs = 0.0f;
#pragma unroll
    for (int i = 0; i < 16; i++) { p[i] = __expf(p[i] - mnew); rs += p[i]; }
    rs += __shfl_xor(rs, 16);
    rs += __shfl_xor(rs, 32);
    lstate = lstate * alpha + rs;

    // P -> p_sm (swizzled [q][kv]): kv = mi*16+quad*4+g, chunk cw = mi*2+(quad>>1)
#pragma unroll
    for (int mi = 0; mi < 4; mi++) {
      bf16x4 pk = { (__bf16)p[mi*4+0], (__bf16)p[mi*4+1], (__bf16)p[mi*4+2], (__bf16)p[mi*4+3] };
      const int cw = mi * 2 + (quad >> 1);
      *(bf16x4*)(&p_sm[wave][r * 64 + ((cw ^ (r & 7)) * 8) + (quad & 1) * 4]) = pk;
    }
    LGKM0();   // wave-private LDS ordering (write -> read below)

    // O rescale: alpha is quad-replicated per q-row -> fetch rows quad*4+g via shfl
    {
      const float a0 = __shfl(alpha, quad * 4 + 0);
      const float a1 = __shfl(alpha, quad * 4 + 1);
      const float a2 = __shfl(alpha, quad * 4 + 2);
      const float a3 = __shfl(alpha, quad * 4 + 3);
#pragma unroll
      for (int dt = 0; dt < 8; dt++) {
        Oacc[dt][0] *= a0; Oacc[dt][1] *= a1; Oacc[dt][2] *= a2; Oacc[dt][3] *= a3;
      }
    }

    // O += P·V  (A = P[q][kv] from p_sm, B = V^T[d][kv] from v_sm)
    __builtin_amdgcn_s_setprio(1);
#pragma unroll
    for (int kk = 0; kk < 2; kk++) {
      bf16x8 pf = *(const bf16x8*)(&p_sm[wave][r * 64 + (((kk * 4 + quad) ^ (r & 7)) * 8)]);
#pragma unroll
      for (int dt = 0; dt < 8; dt++) {
        bf16x8 vf = *(const bf16x8*)(v_sm + (dt * 16 + r) * 64 + (((kk * 4 + quad) ^ (r & 7)) * 8));
        Oacc[dt] = __builtin_amdgcn_mfma_f32_16x16x32_bf16(pf, vf, Oacc[dt], 0, 0, 0);
      }
    }
    __builtin_amdgcn_s_setprio(0);
  }

  // epilogue: l broadcast via shfl (lstate quad-replicated per q-row)
  const float il0 = 1.0f / __shfl(lstate, quad * 4 + 0);
  const float il1 = 1.0f / __shfl(lstate, quad * 4 + 1);
  const float il2 = 1.0f / __shfl(lstate, quad * 4 + 2);
  const float il3 = 1.0f / __shfl(lstate, quad * 4 + 3);
#pragma unroll
  for (int dt = 0; dt < 8; dt++) {
    const int col = h * 128 + dt * 16 + r;
    const int row = tq0 + wave * 16 + quad * 4;
    y[((size_t)(b * 2048 + row + 0)) * 4096 + col] = (__bf16)(Oacc[dt][0] * il0);
    y[((size_t)(b * 2048 + row + 1)) * 4096 + col] = (__bf16)(Oacc[dt][1] * il1);
    y[((size_t)(b * 2048 + row + 2)) * 4096 + col] = (__bf16)(Oacc[dt][2] * il2);
    y[((size_t)(b * 2048 + row + 3)) * 4096 + col] = (__bf16)(Oacc[dt][3] * il3);
  }
}

// ---------------------------------------------------------------------------
extern "C" void kernel_launch(void* const* d_in, const int* in_sizes, int n_in,
                              void* d_out, int out_size, void* d_ws, size_t ws_size,
                              hipStream_t stream)
{
  const float* x  = (const float*)d_in[0];
  // d_in[1] = mask (pure causal triu -> analytic)
  const float* wq = (const float*)d_in[2];
  const float* wk = (const float*)d_in[3];
  const float* wv = (const float*)d_in[4];
  const float* wo = (const float*)d_in[5];
  float* out = (float*)d_out;

  __bf16* ws  = (__bf16*)d_ws;
  __bf16* xb  = ws;                         // [4096][4096]
  __bf16* wT  = xb  + (size_t)16777216;     // [6144][4096]
  __bf16* qkv = wT  + (size_t)25165824;     // [4096][6144]
  __bf16* qr  = qkv + (size_t)25165824;     // [2][32][2048][128]
  __bf16* kr  = qr  + (size_t)16777216;     // [2][8][2048][128]
  __bf16* vT  = kr  + (size_t)4194304;      // [2][8][128][2048]
  __bf16* y   = xb;                         // alias: xb dead after gemm1
  __bf16* woT = wT;                         // alias: wT dead after gemm1

  dim3 blk(256);
  convert_k<<<dim3(16384), blk, 0, stream>>>(x, xb, 16777216L);
  transpose_f32_bf16_k<<<dim3(64, 64), blk, 0, stream>>>(wq, wT,                     4096L, 4096L);
  transpose_f32_bf16_k<<<dim3(16, 64), blk, 0, stream>>>(wk, wT + (size_t)4096*4096, 1024L, 4096L);
  transpose_f32_bf16_k<<<dim3(16, 64), blk, 0, stream>>>(wv, wT + (size_t)5120*4096, 1024L, 4096L);
  gemm256<__bf16, 3><<<dim3(32, 16), dim3(512), 0, stream>>>(xb, wT, qkv, 4096, 6144, 4096);
  transpose_f32_bf16_k<<<dim3(64, 64), blk, 0, stream>>>(wo, woT, 4096L, 4096L);
  rope_k<<<dim3(4096), blk, 0, stream>>>(qkv, qr, kr);
  transpose_bf16_k<<<dim3(2, 32, 16), blk, 0, stream>>>(qkv + 5120, vT, 6144L, 2048L,
                                                        8, (long)2048 * 6144, 128L, (long)128 * 2048);
  flash_k<<<dim3(64, 32), blk, 0, stream>>>(qr, kr, vT, y);
  gemm256<float, 4><<<dim3(16, 16), dim3(512), 0, stream>>>(y, woT, out, 4096, 4096, 4096);
}